// Round 14
// baseline (144.333 us; speedup 1.0000x reference)
//
#include <hip/hip_runtime.h>
#include <hip/hip_bf16.h>
#include <math.h>

// Problem constants
static constexpr int kB = 8;
static constexpr int kH = 8;
static constexpr int kL = 512;
static constexpr int kD = 512;
static constexpr int kDH = 64;     // D/H
static constexpr int kBH = 64;     // B*H
static constexpr int kROWS = kBH * kL;  // 32768

typedef short bf16x8 __attribute__((ext_vector_type(8)));
typedef float f32x4 __attribute__((ext_vector_type(4)));

// RNE float->bf16 (finite inputs only)
__device__ __forceinline__ ushort f2bf(float f) {
    unsigned u = __float_as_uint(f);
    unsigned r = u + 0x7fffu + ((u >> 16) & 1u);
    return (ushort)(r >> 16);
}
__device__ __forceinline__ float bf2f(ushort h) {
    return __uint_as_float((unsigned)h << 16);
}
// order-isomorphic float<->uint maps (finite, no NaN; -0.0 < +0.0 in key order)
__device__ __forceinline__ unsigned mapf(float f) {
    unsigned u = __float_as_uint(f);
    return (u & 0x80000000u) ? ~u : (u | 0x80000000u);
}
__device__ __forceinline__ float unmapf(unsigned u) {
    return (u & 0x80000000u) ? __uint_as_float(u ^ 0x80000000u)
                             : __uint_as_float(~u);
}

// gelu with A&S 7.1.26 erf (max abs err ~1.5e-7, monotone-preserving)
__device__ __forceinline__ float gelu_fast(float v) {
    float z = v * 0.70710678118654752440f;
    float az = fabsf(z);
    float t = 1.0f / (1.0f + 0.3275911f * az);
    float ex = __expf(-az * az);
    float poly = t * (0.254829592f + t * (-0.284496736f + t * (1.421413741f +
                 t * (-1.453152027f + t * 1.061405429f))));
    float erfv = 1.0f - poly * ex;
    erfv = (z < 0.0f) ? -erfv : erfv;
    return 0.5f * v * (1.0f + erfv);
}

// ---------------------------------------------------------------------------
// K1: q = xh@W1^T + b1, k = xh@W2^T + b2 as tiled GEMM (fp32 FMA).
// Epilogue writes hi/lo bf16 pairs directly.
// ---------------------------------------------------------------------------
__global__ __launch_bounds__(256) void k_qk(const float* __restrict__ x,
        const float* __restrict__ W1, const float* __restrict__ b1,
        const float* __restrict__ W2, const float* __restrict__ b2,
        ushort* __restrict__ qh, ushort* __restrict__ ql,
        ushort* __restrict__ kh, ushort* __restrict__ kl) {
    int blk = blockIdx.x;              // b*64 + h*8 + lt
    int b = blk >> 6, h = (blk >> 3) & 7, lt = blk & 7;
    __shared__ float xt[64][68];       // [l][c]
    __shared__ float w1t[64][68];      // [d][c]
    __shared__ float w2t[64][68];
    int tid = threadIdx.x;
    #pragma unroll
    for (int r = 0; r < 16; ++r) {
        int e = tid + r * 256;
        int rr = e >> 6, cc = e & 63;
        xt[rr][cc]  = x[(b * kL + lt * 64 + rr) * kD + h * kDH + cc];
        w1t[rr][cc] = W1[rr * 64 + cc];
        w2t[rr][cc] = W2[rr * 64 + cc];
    }
    __syncthreads();
    int ty = tid >> 4, tx = tid & 15;
    float aq[4][4] = {}, ak[4][4] = {};
    #pragma unroll 2
    for (int c = 0; c < 64; c += 4) {
        float4 av[4], wq[4], wk[4];
        #pragma unroll
        for (int a = 0; a < 4; ++a) av[a] = *(const float4*)&xt[ty * 4 + a][c];
        #pragma unroll
        for (int j = 0; j < 4; ++j) {
            wq[j] = *(const float4*)&w1t[tx + 16 * j][c];
            wk[j] = *(const float4*)&w2t[tx + 16 * j][c];
        }
        #pragma unroll
        for (int a = 0; a < 4; ++a)
            #pragma unroll
            for (int j = 0; j < 4; ++j) {
                aq[a][j] = fmaf(av[a].x, wq[j].x, aq[a][j]);
                aq[a][j] = fmaf(av[a].y, wq[j].y, aq[a][j]);
                aq[a][j] = fmaf(av[a].z, wq[j].z, aq[a][j]);
                aq[a][j] = fmaf(av[a].w, wq[j].w, aq[a][j]);
                ak[a][j] = fmaf(av[a].x, wk[j].x, ak[a][j]);
                ak[a][j] = fmaf(av[a].y, wk[j].y, ak[a][j]);
                ak[a][j] = fmaf(av[a].z, wk[j].z, ak[a][j]);
                ak[a][j] = fmaf(av[a].w, wk[j].w, ak[a][j]);
            }
    }
    #pragma unroll
    for (int a = 0; a < 4; ++a)
        #pragma unroll
        for (int j = 0; j < 4; ++j) {
            int row = lt * 64 + ty * 4 + a;
            int col = tx + 16 * j;
            int o = ((b * kH + h) * kL + row) * kDH + col;
            float qv = aq[a][j] + b1[col];
            float kv = ak[a][j] + b2[col];
            ushort qhh = f2bf(qv), khh = f2bf(kv);
            qh[o] = qhh; ql[o] = f2bf(qv - bf2f(qhh));
            kh[o] = khh; kl[o] = f2bf(kv - bf2f(khh));
        }
}

// ---------------------------------------------------------------------------
// K2+K3 fused (k_adjsel): block = (bh, 16-row strip).
// Phase 1 (MFMA, split-bf16): adj strip 16x512 = gelu(q_strip @ k^T), q
// staged hi/lo once, k-tiles streamed per jt; wave w owns col-frags
// w*16 + m*64 (one frag per wave per jt). Gelu -> LDS strip [16][516] fp32.
// Phase 2: per wave, 4 rows serially: radix-4 integer-key ballot bisection
// (exact 256th-smallest), threshold, logits (j = t*64+lane), softmax-3,
// top-p, analytic masks, row softmax (no max-subtract), bf16 adjb write.
// Eliminates the 67MB+67MB adj global round-trip. grid = 64*32 = 2048.
// ---------------------------------------------------------------------------
__global__ __launch_bounds__(256) void k_adjsel(const ushort* __restrict__ qh,
        const ushort* __restrict__ ql, const ushort* __restrict__ kh,
        const ushort* __restrict__ kl, const float* __restrict__ Wg,
        ushort* __restrict__ adjb,
        float* __restrict__ spbuf, float* __restrict__ entbuf) {
    __shared__ ushort qhs[16][72], qls[16][72];
    __shared__ ushort khs[64][72], kls[64][72];
    __shared__ float adjt[16][516];
    int tid = threadIdx.x;
    int blk = blockIdx.x;
    int bh = blk >> 5, rt = blk & 31;
    int lane = tid & 63, wv = tid >> 6;

    // stage q strip (16 x 64) hi/lo
    {
        int row = tid >> 4, col = (tid & 15) * 4;
        size_t off = (size_t)(bh * kL + rt * 16 + row) * kDH + col;
        *(uint2*)&qhs[row][col] = *(const uint2*)&qh[off];
        *(uint2*)&qls[row][col] = *(const uint2*)&ql[off];
    }

    int coff = (lane >> 4) * 8;
    int arow = lane & 15;
    int brow = wv * 16 + (lane & 15);
    int rs = tid >> 2, ss = tid & 3;
    f32x4 acc[8] = {};
    #pragma unroll
    for (int jt = 0; jt < 8; ++jt) {
        __syncthreads();       // prior-iter MFMA reads done (also covers q stage)
        size_t boff = (size_t)(bh * kL + jt * 64 + rs) * kDH + ss * 16;
        *(int4*)&khs[rs][ss * 16]     = *(const int4*)&kh[boff];
        *(int4*)&khs[rs][ss * 16 + 8] = *(const int4*)&kh[boff + 8];
        *(int4*)&kls[rs][ss * 16]     = *(const int4*)&kl[boff];
        *(int4*)&kls[rs][ss * 16 + 8] = *(const int4*)&kl[boff + 8];
        __syncthreads();
        #pragma unroll
        for (int kk = 0; kk < 2; ++kk) {
            bf16x8 ah8 = *(const bf16x8*)&qhs[arow][kk * 32 + coff];
            bf16x8 al8 = *(const bf16x8*)&qls[arow][kk * 32 + coff];
            bf16x8 bh8 = *(const bf16x8*)&khs[brow][kk * 32 + coff];
            bf16x8 bl8 = *(const bf16x8*)&kls[brow][kk * 32 + coff];
            acc[jt] = __builtin_amdgcn_mfma_f32_16x16x32_bf16(ah8, bh8, acc[jt], 0, 0, 0);
            acc[jt] = __builtin_amdgcn_mfma_f32_16x16x32_bf16(ah8, bl8, acc[jt], 0, 0, 0);
            acc[jt] = __builtin_amdgcn_mfma_f32_16x16x32_bf16(al8, bh8, acc[jt], 0, 0, 0);
        }
    }
    // gelu -> LDS strip
    __syncthreads();
    #pragma unroll
    for (int m = 0; m < 8; ++m) {
        int col = wv * 16 + m * 64 + (lane & 15);
        #pragma unroll
        for (int rr = 0; rr < 4; ++rr) {
            int row = (lane >> 4) * 4 + rr;
            adjt[row][col] = gelu_fast(acc[m][rr]);
        }
    }
    __syncthreads();

    // hoist Wg fragments (j = t*64 + lane; shared by this wave's 4 rows)
    float wgA[8], wgB[8], wgC[8];
    #pragma unroll
    for (int t = 0; t < 8; ++t) {
        wgA[t] = Wg[t * 64 + lane];
        wgB[t] = Wg[kL + t * 64 + lane];
        wgC[t] = Wg[2 * kL + t * 64 + lane];
    }

    // phase 2: wave wv handles strip rows wv*4 .. wv*4+3
    for (int rsel = 0; rsel < 4; ++rsel) {
        int rl = wv * 4 + rsel;
        int i = rt * 16 + rl;           // global row index within (bh) panel
        int rowg = bh * kL + i;
        float v[8];
        unsigned key[8];
        #pragma unroll
        for (int t = 0; t < 8; ++t) {
            v[t] = adjt[rl][t * 64 + lane];
            key[t] = mapf(v[t]);
        }

        // radix-4 bisection, k = 255 (0-indexed), integer key space
        unsigned prefix = 0;
        int cbp = 0, cin = 512;
        int bit = 31;
        int mode = 0;               // 0: exhausted, 1: extract-min, 2: extract-max
        while (bit >= 1) {
            unsigned qsz = 1u << (bit - 1);
            unsigned q1 = prefix + qsz;
            unsigned q2 = prefix + 2u * qsz;
            unsigned q3 = prefix + 3u * qsz;
            int c1 = 0, c2 = 0, c3 = 0;
            #pragma unroll
            for (int t = 0; t < 8; ++t) {
                c1 += (int)__popcll(__ballot(key[t] < q1));
                c2 += (int)__popcll(__ballot(key[t] < q2));
                c3 += (int)__popcll(__ballot(key[t] < q3));
            }
            if (255 < c1)      { cin = c1 - cbp; }
            else if (255 < c2) { cin = c2 - c1;  prefix = q1; cbp = c1; }
            else if (255 < c3) { cin = c3 - c2;  prefix = q2; cbp = c2; }
            else               { cin = cin - (c3 - cbp); prefix = q3; cbp = c3; }
            bit -= 2;
            int loc = 255 - cbp;
            if (cin == 1)        { mode = 2; break; }
            if (loc == 0)        { mode = 1; break; }
            if (loc == cin - 1)  { mode = 2; break; }
        }
        float thr;
        if (mode == 0) {
            thr = unmapf(prefix);
        } else {
            unsigned width = 1u << (bit + 1);   // bit in [-1,29]
            unsigned accu = (mode == 1) ? 0xFFFFFFFFu : 0u;
            #pragma unroll
            for (int t = 0; t < 8; ++t) {
                unsigned d = key[t] - prefix;
                bool mem = d < width;
                if (mode == 1) accu = (mem && key[t] < accu) ? key[t] : accu;
                else           accu = (mem && key[t] > accu) ? key[t] : accu;
            }
            if (mode == 1) {
                #pragma unroll
                for (int off = 1; off < 64; off <<= 1)
                    accu = min(accu, (unsigned)__shfl_xor((int)accu, off));
            } else {
                #pragma unroll
                for (int off = 1; off < 64; off <<= 1)
                    accu = max(accu, (unsigned)__shfl_xor((int)accu, off));
            }
            thr = unmapf(accu);
        }

        // threshold + logits
        float l0 = 0.f, l1 = 0.f, l2 = 0.f;
        #pragma unroll
        for (int t = 0; t < 8; ++t) {
            float nv = (v[t] > thr) ? v[t] : 0.0f;
            v[t] = nv;
            l0 = fmaf(nv, wgA[t], l0);
            l1 = fmaf(nv, wgB[t], l1);
            l2 = fmaf(nv, wgC[t], l2);
        }
        #pragma unroll
        for (int off = 1; off < 64; off <<= 1) {
            l0 += __shfl_xor(l0, off);
            l1 += __shfl_xor(l1, off);
            l2 += __shfl_xor(l2, off);
        }
        // softmax-3 + stable top-p (wave-uniform)
        float m = fmaxf(l0, fmaxf(l1, l2));
        float e0 = __expf(l0 - m), e1 = __expf(l1 - m), e2 = __expf(l2 - m);
        float s = e0 + e1 + e2;
        float p[3] = {e0 / s, e1 / s, e2 / s};
        int o0, o1, o2;
        if (p[0] >= p[1] && p[0] >= p[2]) o0 = 0;
        else if (p[1] >= p[2]) o0 = 1;
        else o0 = 2;
        int r0 = (o0 == 0) ? 1 : 0;
        int r1 = (o0 == 2) ? 1 : 2;
        if (p[r0] >= p[r1]) { o1 = r0; o2 = r1; } else { o1 = r1; o2 = r0; }
        float sp0 = p[o0], sp1 = p[o1], sp2 = p[o2];
        float c0 = sp0, c1 = sp0 + sp1, c2 = c1 + sp2;
        bool m0 = c0 > 0.5f, m1 = c1 > 0.5f, m2 = c2 > 0.5f;
        int ti = m0 ? 0 : (m1 ? 1 : 2);
        bool mm0 = m0 && (ti != 0);
        bool mm1 = m1 && (ti != 1);
        bool mm2 = m2 && (ti != 2);
        float g[3] = {0.f, 0.f, 0.f};
        g[o0] = mm0 ? 0.f : 1.f;
        g[o1] = mm1 ? 0.f : 1.f;
        g[o2] = mm2 ? 0.f : 1.f;
        if (lane == 0) {
            spbuf[rowg * 3 + 0] = mm0 ? 0.f : sp0;
            spbuf[rowg * 3 + 1] = mm1 ? 0.f : sp1;
            spbuf[rowg * 3 + 2] = mm2 ? 0.f : sp2;
            entbuf[rowg] = p[0] * __logf(p[0] + 1e-10f) +
                           p[1] * __logf(p[1] + 1e-10f) +
                           p[2] * __logf(p[2] + 1e-10f);
        }

        // analytic masks for j = t*64 + lane:
        //   T (same 64-block, t==i6): g1; diag (also lane==i63): g1+1
        //   S (same residue, lane==i63, t!=i6): g0 ; else g2
        int i6 = i >> 6, i63 = i & 63;
        bool ing = (lane == i63);
        float selT = ing ? (g[1] + 1.0f) : g[1];
        float selO = ing ? g[0] : g[2];
        // row softmax without max-subtract (|av| <= ~30 -> exp safe in fp32)
        float e[8], ls = 0.f;
        #pragma unroll
        for (int t = 0; t < 8; ++t) {
            float mm = (t == i6) ? selT : selO;
            float av = v[t] * mm;
            e[t] = __expf(av);
            ls += e[t];
        }
        #pragma unroll
        for (int off = 1; off < 64; off <<= 1) ls += __shfl_xor(ls, off);
        float inv = 1.0f / ls;
        #pragma unroll
        for (int t = 0; t < 8; ++t)
            adjb[(size_t)rowg * kL + t * 64 + lane] = f2bf(e[t] * inv);
    }
}

// ---------------------------------------------------------------------------
// K4 (MFMA, bf16): xp = x @ Wp^T + bp, written TRANSPOSED bf16:
// xpbT[dcol][b*L + l].
// ---------------------------------------------------------------------------
__global__ __launch_bounds__(256) void k_xp(const float* __restrict__ x,
        const float* __restrict__ Wp, const float* __restrict__ bp,
        ushort* __restrict__ xpbT) {
    int it = blockIdx.x >> 3, jt = blockIdx.x & 7;   // it: l-rows, jt: d-cols
    __shared__ ushort xbs[64][72];
    __shared__ ushort wbs[64][72];
    int tid = threadIdx.x;
    int r = tid >> 2, s = tid & 3;
    int lane = tid & 63, wave = tid >> 6;
    int wm = wave >> 1, wn = wave & 1;
    int am = wm * 32 + (lane & 15);
    int bn = wn * 32 + (lane & 15);
    int coff = (lane >> 4) * 8;
    f32x4 acc[2][2] = {};
    const float* xsrc = x + (size_t)(it * 64 + r) * kD + s * 16;
    const float* wsrc = Wp + (size_t)(jt * 64 + r) * kD + s * 16;
    for (int kt = 0; kt < 8; ++kt) {
        union { ushort u[16]; int4 v[2]; } px, pw;
        #pragma unroll
        for (int c4 = 0; c4 < 4; ++c4) {
            float4 fx = *(const float4*)(xsrc + kt * 64 + c4 * 4);
            float4 fw = *(const float4*)(wsrc + kt * 64 + c4 * 4);
            px.u[c4 * 4 + 0] = f2bf(fx.x); px.u[c4 * 4 + 1] = f2bf(fx.y);
            px.u[c4 * 4 + 2] = f2bf(fx.z); px.u[c4 * 4 + 3] = f2bf(fx.w);
            pw.u[c4 * 4 + 0] = f2bf(fw.x); pw.u[c4 * 4 + 1] = f2bf(fw.y);
            pw.u[c4 * 4 + 2] = f2bf(fw.z); pw.u[c4 * 4 + 3] = f2bf(fw.w);
        }
        __syncthreads();
        *(int4*)&xbs[r][s * 16] = px.v[0];
        *(int4*)&xbs[r][s * 16 + 8] = px.v[1];
        *(int4*)&wbs[r][s * 16] = pw.v[0];
        *(int4*)&wbs[r][s * 16 + 8] = pw.v[1];
        __syncthreads();
        #pragma unroll
        for (int kk = 0; kk < 2; ++kk) {
            bf16x8 af[2], bf[2];
            #pragma unroll
            for (int fm = 0; fm < 2; ++fm)
                af[fm] = *(const bf16x8*)&xbs[am + fm * 16][kk * 32 + coff];
            #pragma unroll
            for (int fn = 0; fn < 2; ++fn)
                bf[fn] = *(const bf16x8*)&wbs[bn + fn * 16][kk * 32 + coff];
            #pragma unroll
            for (int fm = 0; fm < 2; ++fm)
                #pragma unroll
                for (int fn = 0; fn < 2; ++fn)
                    acc[fm][fn] = __builtin_amdgcn_mfma_f32_16x16x32_bf16(
                        af[fm], bf[fn], acc[fm][fn], 0, 0, 0);
        }
    }
    // epilogue: add bias, store transposed (4 consecutive l per lane)
    #pragma unroll
    for (int fn = 0; fn < 2; ++fn) {
        int dcol = jt * 64 + wn * 32 + (lane & 15) + fn * 16;
        float bpv = bp[dcol];
        #pragma unroll
        for (int fm = 0; fm < 2; ++fm) {
            int l0 = it * 64 + wm * 32 + fm * 16 + (lane >> 4) * 4;
            union { ushort u[4]; uint2 v; } pk;
            #pragma unroll
            for (int rr = 0; rr < 4; ++rr)
                pk.u[rr] = f2bf(acc[fm][fn][rr] + bpv);
            *(uint2*)&xpbT[(size_t)dcol * (size_t)(kB * kL) + l0] = pk.v;
        }
    }
}

// ---------------------------------------------------------------------------
// K6 (MFMA): out[b, i, h*64+d] = sum_j adjb[bh,i,j] * xpbT[h*64+d][b*512+j]
// ---------------------------------------------------------------------------
__global__ __launch_bounds__(256) void k_out(const ushort* __restrict__ adjb,
        const ushort* __restrict__ xpbT, float* __restrict__ out) {
    int blk = blockIdx.x;
    int bh = blk >> 3, it = blk & 7;
    int b = bh >> 3, h = bh & 7;
    __shared__ ushort as_[64][72];
    __shared__ ushort bs_[64][72];
    int tid = threadIdx.x;
    int lane = tid & 63, wave = tid >> 6;
    int wm = wave >> 1, wn = wave & 1;
    int r = tid >> 2, s = tid & 3;
    const ushort* aG = adjb + ((size_t)(bh * kL + it * 64 + r)) * kL + s * 16;
    const ushort* bG = xpbT + ((size_t)(h * kDH + r)) * (size_t)(kB * kL) + b * kL + s * 16;
    f32x4 acc[2][2] = {};
    int am = wm * 32 + (lane & 15);
    int bn = wn * 32 + (lane & 15);
    int coff = (lane >> 4) * 8;
    for (int kt = 0; kt < 8; ++kt) {
        int4 a0 = *(const int4*)(aG + kt * 64);
        int4 a1 = *(const int4*)(aG + kt * 64 + 8);
        int4 b0 = *(const int4*)(bG + kt * 64);
        int4 b1 = *(const int4*)(bG + kt * 64 + 8);
        __syncthreads();
        *(int4*)&as_[r][s * 16] = a0;
        *(int4*)&as_[r][s * 16 + 8] = a1;
        *(int4*)&bs_[r][s * 16] = b0;
        *(int4*)&bs_[r][s * 16 + 8] = b1;
        __syncthreads();
        #pragma unroll
        for (int kk = 0; kk < 2; ++kk) {
            bf16x8 af[2], bf[2];
            #pragma unroll
            for (int fm = 0; fm < 2; ++fm)
                af[fm] = *(const bf16x8*)&as_[am + fm * 16][kk * 32 + coff];
            #pragma unroll
            for (int fn = 0; fn < 2; ++fn)
                bf[fn] = *(const bf16x8*)&bs_[bn + fn * 16][kk * 32 + coff];
            #pragma unroll
            for (int fm = 0; fm < 2; ++fm)
                #pragma unroll
                for (int fn = 0; fn < 2; ++fn)
                    acc[fm][fn] = __builtin_amdgcn_mfma_f32_16x16x32_bf16(
                        af[fm], bf[fn], acc[fm][fn], 0, 0, 0);
        }
    }
    int mrow = it * 64 + wm * 32 + (lane >> 4) * 4;
    int ncol = h * kDH + wn * 32 + (lane & 15);
    #pragma unroll
    for (int fm = 0; fm < 2; ++fm)
        #pragma unroll
        for (int fn = 0; fn < 2; ++fn)
            #pragma unroll
            for (int rr = 0; rr < 4; ++rr)
                out[((size_t)b * kL + mrow + fm * 16 + rr) * kD + ncol + fn * 16] =
                    acc[fm][fn][rr];
}

// ---------------------------------------------------------------------------
// K7a: loss stage 1. Blocks 0..5: imps[idx] = sum_bh spbuf[bh*1536+idx]
// (256 idx per block). Blocks 6..37: entropy partial sums (1024 elems each).
// ---------------------------------------------------------------------------
__global__ __launch_bounds__(256) void k_loss1(const float* __restrict__ spbuf,
        const float* __restrict__ entbuf, float* __restrict__ imps_buf,
        float* __restrict__ entpart) {
    int tid = threadIdx.x;
    int blk = blockIdx.x;
    if (blk < 6) {
        int idx = blk * 256 + tid;      // < 1536
        float s = 0.f;
        for (int bh = 0; bh < kBH; ++bh)
            s += spbuf[bh * (kL * 3) + idx];
        imps_buf[idx] = s;
    } else {
        int eb = blk - 6;               // 0..31
        const float* src = entbuf + eb * 1024 + tid * 4;
        float4 v4 = *(const float4*)src;
        float s = v4.x + v4.y + v4.z + v4.w;
        __shared__ float red[256];
        red[tid] = s;
        __syncthreads();
        for (int st = 128; st > 0; st >>= 1) {
            if (tid < st) red[tid] += red[tid + st];
            __syncthreads();
        }
        if (tid == 0) entpart[eb] = red[0];
    }
}

// ---------------------------------------------------------------------------
// K7b: loss stage 2 (single block): mean/var of imps (ddof=1) + entropy total
// ---------------------------------------------------------------------------
__global__ __launch_bounds__(256) void k_loss2(const float* __restrict__ imps_buf,
        const float* __restrict__ entpart, float* __restrict__ out_loss) {
    __shared__ float red[256];
    int tid = threadIdx.x;
    float im[6];
    #pragma unroll
    for (int t = 0; t < 6; ++t) im[t] = imps_buf[t * 256 + tid];
    float ms = im[0] + im[1] + im[2] + im[3] + im[4] + im[5];
    red[tid] = ms;
    __syncthreads();
    for (int st = 128; st > 0; st >>= 1) {
        if (tid < st) red[tid] += red[tid + st];
        __syncthreads();
    }
    float mean = red[0] / (float)(kL * 3);
    __syncthreads();
    float vs = 0.f;
    #pragma unroll
    for (int t = 0; t < 6; ++t) { float d = im[t] - mean; vs = fmaf(d, d, vs); }
    red[tid] = vs;
    __syncthreads();
    for (int st = 128; st > 0; st >>= 1) {
        if (tid < st) red[tid] += red[tid + st];
        __syncthreads();
    }
    float var = red[0] / (float)(kL * 3 - 1);
    __syncthreads();
    red[tid] = (tid < 32) ? entpart[tid] : 0.f;
    __syncthreads();
    for (int st = 128; st > 0; st >>= 1) {
        if (tid < st) red[tid] += red[tid + st];
        __syncthreads();
    }
    if (tid == 0) {
        float loss_imp = var / (mean * mean + 1e-10f);
        float loss_dyn = -red[0] / (float)(kBH * 3);
        out_loss[0] = loss_imp + 0.1f * loss_dyn;
    }
}

// ---------------------------------------------------------------------------
extern "C" void kernel_launch(void* const* d_in, const int* in_sizes, int n_in,
                              void* d_out, int out_size, void* d_ws, size_t ws_size,
                              hipStream_t stream) {
    const float* x     = (const float*)d_in[0];
    const float* W1    = (const float*)d_in[2];
    const float* b1    = (const float*)d_in[3];
    const float* W2    = (const float*)d_in[4];
    const float* b2    = (const float*)d_in[5];
    const float* Wg    = (const float*)d_in[6];
    const float* Wp    = (const float*)d_in[7];
    const float* bp    = (const float*)d_in[8];
    float* out = (float*)d_out;
    float* ws  = (float*)d_ws;

    // workspace layout (float units). No adj buffer anymore; adjb must NOT
    // overlap qh..kl (live simultaneously inside k_adjsel).
    ushort* qh     = (ushort*)(ws);               // 2,097,152 ushorts each
    ushort* ql     = (ushort*)(ws + 1048576);
    ushort* kh     = (ushort*)(ws + 2097152);
    ushort* kl     = (ushort*)(ws + 3145728);
    ushort* adjb   = (ushort*)(ws + 4194304);     // 16,777,216 ushorts
    ushort* xpbT   = (ushort*)(ws + 12582912);    //  2,097,152 ushorts
    float*  spbuf  = ws + 13631488;               // 98,304
    float*  entbuf = ws + 13729792;               // 32,768
    float*  imps_b = ws + 13762560;               // 1,536
    float*  entprt = ws + 13764096;               // 32

    k_qk<<<512, 256, 0, stream>>>(x, W1, b1, W2, b2, qh, ql, kh, kl);
    k_adjsel<<<kBH * 32, 256, 0, stream>>>(qh, ql, kh, kl, Wg, adjb, spbuf, entbuf);
    k_xp<<<512, 256, 0, stream>>>(x, Wp, bp, xpbT);
    k_out<<<512, 256, 0, stream>>>(adjb, xpbT, out);
    k_loss1<<<38, 256, 0, stream>>>(spbuf, entbuf, imps_b, entprt);
    k_loss2<<<1, 256, 0, stream>>>(imps_b, entprt, out + (size_t)kB * kL * kD);
}

// Round 15
// 102.263 us; speedup vs baseline: 1.4114x; 1.4114x over previous
//
#include <hip/hip_runtime.h>
#include <hip/hip_bf16.h>
#include <math.h>

// Problem constants
static constexpr int kB = 8;
static constexpr int kH = 8;
static constexpr int kL = 512;
static constexpr int kD = 512;
static constexpr int kDH = 64;     // D/H
static constexpr int kBH = 64;     // B*H
static constexpr int kROWS = kBH * kL;  // 32768

typedef short bf16x8 __attribute__((ext_vector_type(8)));
typedef float f32x4 __attribute__((ext_vector_type(4)));

// RNE float->bf16 (finite inputs only)
__device__ __forceinline__ ushort f2bf(float f) {
    unsigned u = __float_as_uint(f);
    unsigned r = u + 0x7fffu + ((u >> 16) & 1u);
    return (ushort)(r >> 16);
}
__device__ __forceinline__ float bf2f(ushort h) {
    return __uint_as_float((unsigned)h << 16);
}
// order-isomorphic float<->uint maps (finite, no NaN; -0.0 < +0.0 in key order)
__device__ __forceinline__ unsigned mapf(float f) {
    unsigned u = __float_as_uint(f);
    return (u & 0x80000000u) ? ~u : (u | 0x80000000u);
}
__device__ __forceinline__ float unmapf(unsigned u) {
    return (u & 0x80000000u) ? __uint_as_float(u ^ 0x80000000u)
                             : __uint_as_float(~u);
}

// gelu with A&S 7.1.26 erf (max abs err ~1.5e-7, monotone-preserving)
__device__ __forceinline__ float gelu_fast(float v) {
    float z = v * 0.70710678118654752440f;
    float az = fabsf(z);
    float t = 1.0f / (1.0f + 0.3275911f * az);
    float ex = __expf(-az * az);
    float poly = t * (0.254829592f + t * (-0.284496736f + t * (1.421413741f +
                 t * (-1.453152027f + t * 1.061405429f))));
    float erfv = 1.0f - poly * ex;
    erfv = (z < 0.0f) ? -erfv : erfv;
    return 0.5f * v * (1.0f + erfv);
}

// ---------------------------------------------------------------------------
// K1 (merged): blocks 0..511: q/k projection (fp32 FMA, hi/lo bf16 out);
// blocks 512..1023: xp = x @ Wp^T + bp -> transposed bf16 xpbT (MFMA).
// Both branches only read x + weights (independent). LDS aliased.
// ---------------------------------------------------------------------------
__global__ __launch_bounds__(256) void k_qk_xp(const float* __restrict__ x,
        const float* __restrict__ W1, const float* __restrict__ b1,
        const float* __restrict__ W2, const float* __restrict__ b2,
        const float* __restrict__ Wp, const float* __restrict__ bp,
        ushort* __restrict__ qh, ushort* __restrict__ ql,
        ushort* __restrict__ kh, ushort* __restrict__ kl,
        ushort* __restrict__ xpbT) {
    __shared__ __align__(16) char smem[3 * 64 * 68 * 4];
    int tid = threadIdx.x;
    int blk = blockIdx.x;
    if (blk < 512) {
        // ---------------- qk branch ----------------
        int b = blk >> 6, h = (blk >> 3) & 7, lt = blk & 7;
        float (*xt)[68]  = (float(*)[68])smem;
        float (*w1t)[68] = (float(*)[68])(smem + 64 * 68 * 4);
        float (*w2t)[68] = (float(*)[68])(smem + 2 * 64 * 68 * 4);
        #pragma unroll
        for (int r = 0; r < 16; ++r) {
            int e = tid + r * 256;
            int rr = e >> 6, cc = e & 63;
            xt[rr][cc]  = x[(b * kL + lt * 64 + rr) * kD + h * kDH + cc];
            w1t[rr][cc] = W1[rr * 64 + cc];
            w2t[rr][cc] = W2[rr * 64 + cc];
        }
        __syncthreads();
        int ty = tid >> 4, tx = tid & 15;
        float aq[4][4] = {}, ak[4][4] = {};
        #pragma unroll 2
        for (int c = 0; c < 64; c += 4) {
            float4 av[4], wq[4], wk[4];
            #pragma unroll
            for (int a = 0; a < 4; ++a) av[a] = *(const float4*)&xt[ty * 4 + a][c];
            #pragma unroll
            for (int j = 0; j < 4; ++j) {
                wq[j] = *(const float4*)&w1t[tx + 16 * j][c];
                wk[j] = *(const float4*)&w2t[tx + 16 * j][c];
            }
            #pragma unroll
            for (int a = 0; a < 4; ++a)
                #pragma unroll
                for (int j = 0; j < 4; ++j) {
                    aq[a][j] = fmaf(av[a].x, wq[j].x, aq[a][j]);
                    aq[a][j] = fmaf(av[a].y, wq[j].y, aq[a][j]);
                    aq[a][j] = fmaf(av[a].z, wq[j].z, aq[a][j]);
                    aq[a][j] = fmaf(av[a].w, wq[j].w, aq[a][j]);
                    ak[a][j] = fmaf(av[a].x, wk[j].x, ak[a][j]);
                    ak[a][j] = fmaf(av[a].y, wk[j].y, ak[a][j]);
                    ak[a][j] = fmaf(av[a].z, wk[j].z, ak[a][j]);
                    ak[a][j] = fmaf(av[a].w, wk[j].w, ak[a][j]);
                }
        }
        #pragma unroll
        for (int a = 0; a < 4; ++a)
            #pragma unroll
            for (int j = 0; j < 4; ++j) {
                int row = lt * 64 + ty * 4 + a;
                int col = tx + 16 * j;
                int o = ((b * kH + h) * kL + row) * kDH + col;
                float qv = aq[a][j] + b1[col];
                float kv = ak[a][j] + b2[col];
                ushort qhh = f2bf(qv), khh = f2bf(kv);
                qh[o] = qhh; ql[o] = f2bf(qv - bf2f(qhh));
                kh[o] = khh; kl[o] = f2bf(kv - bf2f(khh));
            }
    } else {
        // ---------------- xp branch (MFMA bf16, transposed store) ----------
        int bxp = blk - 512;
        int it = bxp >> 3, jt = bxp & 7;
        ushort (*xbs)[72] = (ushort(*)[72])smem;
        ushort (*wbs)[72] = (ushort(*)[72])(smem + 64 * 72 * 2);
        int r = tid >> 2, s = tid & 3;
        int lane = tid & 63, wave = tid >> 6;
        int wm = wave >> 1, wn = wave & 1;
        int am = wm * 32 + (lane & 15);
        int bn = wn * 32 + (lane & 15);
        int coff = (lane >> 4) * 8;
        f32x4 acc[2][2] = {};
        const float* xsrc = x + (size_t)(it * 64 + r) * kD + s * 16;
        const float* wsrc = Wp + (size_t)(jt * 64 + r) * kD + s * 16;
        for (int kt = 0; kt < 8; ++kt) {
            union { ushort u[16]; int4 v[2]; } px, pw;
            #pragma unroll
            for (int c4 = 0; c4 < 4; ++c4) {
                float4 fx = *(const float4*)(xsrc + kt * 64 + c4 * 4);
                float4 fw = *(const float4*)(wsrc + kt * 64 + c4 * 4);
                px.u[c4 * 4 + 0] = f2bf(fx.x); px.u[c4 * 4 + 1] = f2bf(fx.y);
                px.u[c4 * 4 + 2] = f2bf(fx.z); px.u[c4 * 4 + 3] = f2bf(fx.w);
                pw.u[c4 * 4 + 0] = f2bf(fw.x); pw.u[c4 * 4 + 1] = f2bf(fw.y);
                pw.u[c4 * 4 + 2] = f2bf(fw.z); pw.u[c4 * 4 + 3] = f2bf(fw.w);
            }
            __syncthreads();
            *(int4*)&xbs[r][s * 16] = px.v[0];
            *(int4*)&xbs[r][s * 16 + 8] = px.v[1];
            *(int4*)&wbs[r][s * 16] = pw.v[0];
            *(int4*)&wbs[r][s * 16 + 8] = pw.v[1];
            __syncthreads();
            #pragma unroll
            for (int kk = 0; kk < 2; ++kk) {
                bf16x8 af[2], bf[2];
                #pragma unroll
                for (int fm = 0; fm < 2; ++fm)
                    af[fm] = *(const bf16x8*)&xbs[am + fm * 16][kk * 32 + coff];
                #pragma unroll
                for (int fn = 0; fn < 2; ++fn)
                    bf[fn] = *(const bf16x8*)&wbs[bn + fn * 16][kk * 32 + coff];
                #pragma unroll
                for (int fm = 0; fm < 2; ++fm)
                    #pragma unroll
                    for (int fn = 0; fn < 2; ++fn)
                        acc[fm][fn] = __builtin_amdgcn_mfma_f32_16x16x32_bf16(
                            af[fm], bf[fn], acc[fm][fn], 0, 0, 0);
            }
        }
        #pragma unroll
        for (int fn = 0; fn < 2; ++fn) {
            int dcol = jt * 64 + wn * 32 + (lane & 15) + fn * 16;
            float bpv = bp[dcol];
            #pragma unroll
            for (int fm = 0; fm < 2; ++fm) {
                int l0 = it * 64 + wm * 32 + fm * 16 + (lane >> 4) * 4;
                union { ushort u[4]; uint2 v; } pk;
                #pragma unroll
                for (int rr = 0; rr < 4; ++rr)
                    pk.u[rr] = f2bf(acc[fm][fn][rr] + bpv);
                *(uint2*)&xpbT[(size_t)dcol * (size_t)(kB * kL) + l0] = pk.v;
            }
        }
    }
}

// ---------------------------------------------------------------------------
// K2 (MFMA, split-bf16): adj = gelu(q @ k^T) per (b,h). 64x64 tile, K=64.
// ---------------------------------------------------------------------------
__global__ __launch_bounds__(256) void k_adj(const ushort* __restrict__ qh,
        const ushort* __restrict__ ql, const ushort* __restrict__ kh,
        const ushort* __restrict__ kl, float* __restrict__ adj) {
    int blk = blockIdx.x;
    int bh = blk >> 6;
    int it = (blk >> 3) & 7, jt = blk & 7;
    __shared__ ushort ah[64][72], al[64][72];
    __shared__ ushort bh_[64][72], bl[64][72];
    int tid = threadIdx.x;
    int r = tid >> 2, s = tid & 3;
    size_t aoff = (size_t)(bh * kL + it * 64 + r) * kDH + s * 16;
    size_t boff = (size_t)(bh * kL + jt * 64 + r) * kDH + s * 16;
    *(int4*)&ah[r][s * 16]  = *(const int4*)&qh[aoff];
    *(int4*)&ah[r][s * 16 + 8]  = *(const int4*)&qh[aoff + 8];
    *(int4*)&al[r][s * 16]  = *(const int4*)&ql[aoff];
    *(int4*)&al[r][s * 16 + 8]  = *(const int4*)&ql[aoff + 8];
    *(int4*)&bh_[r][s * 16] = *(const int4*)&kh[boff];
    *(int4*)&bh_[r][s * 16 + 8] = *(const int4*)&kh[boff + 8];
    *(int4*)&bl[r][s * 16]  = *(const int4*)&kl[boff];
    *(int4*)&bl[r][s * 16 + 8]  = *(const int4*)&kl[boff + 8];
    __syncthreads();
    int lane = tid & 63, wave = tid >> 6;
    int wm = wave >> 1, wn = wave & 1;
    int am = wm * 32 + (lane & 15);
    int bn = wn * 32 + (lane & 15);
    int coff = (lane >> 4) * 8;
    f32x4 acc[2][2] = {};
    #pragma unroll
    for (int kk = 0; kk < 2; ++kk) {
        bf16x8 afh[2], afl[2], bfh[2], bfl[2];
        #pragma unroll
        for (int fm = 0; fm < 2; ++fm) {
            afh[fm] = *(const bf16x8*)&ah[am + fm * 16][kk * 32 + coff];
            afl[fm] = *(const bf16x8*)&al[am + fm * 16][kk * 32 + coff];
        }
        #pragma unroll
        for (int fn = 0; fn < 2; ++fn) {
            bfh[fn] = *(const bf16x8*)&bh_[bn + fn * 16][kk * 32 + coff];
            bfl[fn] = *(const bf16x8*)&bl[bn + fn * 16][kk * 32 + coff];
        }
        #pragma unroll
        for (int fm = 0; fm < 2; ++fm)
            #pragma unroll
            for (int fn = 0; fn < 2; ++fn) {
                acc[fm][fn] = __builtin_amdgcn_mfma_f32_16x16x32_bf16(
                    afh[fm], bfh[fn], acc[fm][fn], 0, 0, 0);
                acc[fm][fn] = __builtin_amdgcn_mfma_f32_16x16x32_bf16(
                    afh[fm], bfl[fn], acc[fm][fn], 0, 0, 0);
                acc[fm][fn] = __builtin_amdgcn_mfma_f32_16x16x32_bf16(
                    afl[fm], bfh[fn], acc[fm][fn], 0, 0, 0);
            }
    }
    int mrow = it * 64 + wm * 32 + (lane >> 4) * 4;
    int ncol = jt * 64 + wn * 32 + (lane & 15);
    #pragma unroll
    for (int fm = 0; fm < 2; ++fm)
        #pragma unroll
        for (int fn = 0; fn < 2; ++fn)
            #pragma unroll
            for (int rr = 0; rr < 4; ++rr)
                adj[((size_t)bh * kL + mrow + fm * 16 + rr) * kL + ncol + fn * 16] =
                    gelu_fast(acc[fm][fn][rr]);
}

// ---------------------------------------------------------------------------
// K3 (fused): per-row, one wave. Exact 256th-smallest via RADIX-4 ballot
// bisection (integer key space, -0.0 safe), boundary early-exits, integer
// extraction. Then threshold, logits, softmax-3, top-p, computed masks,
// row softmax (no max-subtract), bf16 adjb write. grid = ROWS/4.
// ---------------------------------------------------------------------------
__global__ __launch_bounds__(256) void k_select(const float* __restrict__ adj,
        const float* __restrict__ Wg,
        ushort* __restrict__ adjb,
        float* __restrict__ spbuf, float* __restrict__ entbuf) {
    int tid = threadIdx.x;
    int wave = tid >> 6, lane = tid & 63;
    int row = blockIdx.x * 4 + wave;
    int i = row & (kL - 1);
    const float* arow = adj + (size_t)row * kL;
    int j0 = lane * 8;

    float v[8];
    {
        float4 a0 = *(const float4*)&arow[j0];
        float4 a1 = *(const float4*)&arow[j0 + 4];
        v[0] = a0.x; v[1] = a0.y; v[2] = a0.z; v[3] = a0.w;
        v[4] = a1.x; v[5] = a1.y; v[6] = a1.z; v[7] = a1.w;
    }
    unsigned key[8];
    #pragma unroll
    for (int t = 0; t < 8; ++t) key[t] = mapf(v[t]);

    // radix-4 bisection, k = 255 (0-indexed), integer key space
    unsigned prefix = 0;
    int cbp = 0, cin = 512;
    int bit = 31;
    int mode = 0;                   // 0: exhausted, 1: extract-min, 2: extract-max
    while (bit >= 1) {
        unsigned qsz = 1u << (bit - 1);
        unsigned q1 = prefix + qsz;
        unsigned q2 = prefix + 2u * qsz;
        unsigned q3 = prefix + 3u * qsz;
        int c1 = 0, c2 = 0, c3 = 0;
        #pragma unroll
        for (int t = 0; t < 8; ++t) {
            c1 += (int)__popcll(__ballot(key[t] < q1));
            c2 += (int)__popcll(__ballot(key[t] < q2));
            c3 += (int)__popcll(__ballot(key[t] < q3));
        }
        if (255 < c1)      { cin = c1 - cbp; }
        else if (255 < c2) { cin = c2 - c1;  prefix = q1; cbp = c1; }
        else if (255 < c3) { cin = c3 - c2;  prefix = q2; cbp = c2; }
        else               { cin = cin - (c3 - cbp); prefix = q3; cbp = c3; }
        bit -= 2;
        int loc = 255 - cbp;        // local rank of kth within interval
        if (cin == 1)        { mode = 2; break; }
        if (loc == 0)        { mode = 1; break; }
        if (loc == cin - 1)  { mode = 2; break; }
    }
    float thr;
    if (mode == 0) {
        thr = unmapf(prefix);       // all bits resolved: exact key
    } else {
        unsigned width = 1u << (bit + 1);   // bit in [-1,29]
        unsigned acc = (mode == 1) ? 0xFFFFFFFFu : 0u;
        #pragma unroll
        for (int t = 0; t < 8; ++t) {
            unsigned d = key[t] - prefix;
            bool mem = d < width;
            if (mode == 1) acc = (mem && key[t] < acc) ? key[t] : acc;
            else           acc = (mem && key[t] > acc) ? key[t] : acc;
        }
        if (mode == 1) {
            #pragma unroll
            for (int off = 1; off < 64; off <<= 1)
                acc = min(acc, (unsigned)__shfl_xor((int)acc, off));
        } else {
            #pragma unroll
            for (int off = 1; off < 64; off <<= 1)
                acc = max(acc, (unsigned)__shfl_xor((int)acc, off));
        }
        thr = unmapf(acc);
    }

    // threshold + logits (Wg as float4)
    union { float4 f4[2]; float f[8]; } wg0, wg1, wg2;
    wg0.f4[0] = *(const float4*)&Wg[j0];          wg0.f4[1] = *(const float4*)&Wg[j0 + 4];
    wg1.f4[0] = *(const float4*)&Wg[kL + j0];     wg1.f4[1] = *(const float4*)&Wg[kL + j0 + 4];
    wg2.f4[0] = *(const float4*)&Wg[2 * kL + j0]; wg2.f4[1] = *(const float4*)&Wg[2 * kL + j0 + 4];
    float l0 = 0.f, l1 = 0.f, l2 = 0.f;
    #pragma unroll
    for (int t = 0; t < 8; ++t) {
        float nv = (v[t] > thr) ? v[t] : 0.0f;
        v[t] = nv;
        l0 = fmaf(nv, wg0.f[t], l0);
        l1 = fmaf(nv, wg1.f[t], l1);
        l2 = fmaf(nv, wg2.f[t], l2);
    }
    #pragma unroll
    for (int off = 1; off < 64; off <<= 1) {
        l0 += __shfl_xor(l0, off);
        l1 += __shfl_xor(l1, off);
        l2 += __shfl_xor(l2, off);
    }
    // softmax-3 + stable top-p (all lanes redundantly; wave-uniform)
    float m = fmaxf(l0, fmaxf(l1, l2));
    float e0 = __expf(l0 - m), e1 = __expf(l1 - m), e2 = __expf(l2 - m);
    float s = e0 + e1 + e2;
    float p[3] = {e0 / s, e1 / s, e2 / s};
    int o0, o1, o2;
    if (p[0] >= p[1] && p[0] >= p[2]) o0 = 0;
    else if (p[1] >= p[2]) o0 = 1;
    else o0 = 2;
    int r0 = (o0 == 0) ? 1 : 0;
    int r1 = (o0 == 2) ? 1 : 2;
    if (p[r0] >= p[r1]) { o1 = r0; o2 = r1; } else { o1 = r1; o2 = r0; }
    float sp0 = p[o0], sp1 = p[o1], sp2 = p[o2];
    float c0 = sp0, c1 = sp0 + sp1, c2 = c1 + sp2;
    bool m0 = c0 > 0.5f, m1 = c1 > 0.5f, m2 = c2 > 0.5f;
    int ti = m0 ? 0 : (m1 ? 1 : 2);
    bool mm0 = m0 && (ti != 0);
    bool mm1 = m1 && (ti != 1);
    bool mm2 = m2 && (ti != 2);
    float g[3] = {0.f, 0.f, 0.f};
    g[o0] = mm0 ? 0.f : 1.f;
    g[o1] = mm1 ? 0.f : 1.f;
    g[o2] = mm2 ? 0.f : 1.f;
    if (lane == 0) {
        spbuf[row * 3 + 0] = mm0 ? 0.f : sp0;
        spbuf[row * 3 + 1] = mm1 ? 0.f : sp1;
        spbuf[row * 3 + 2] = mm2 ? 0.f : sp2;
        entbuf[row] = p[0] * __logf(p[0] + 1e-10f) +
                      p[1] * __logf(p[1] + 1e-10f) +
                      p[2] * __logf(p[2] + 1e-10f);
    }

    // computed masks: S (same mod-64 residue, j!=i) -> g0; T (same 64-block,
    // incl diag) -> g1 (+1 on diag); else -> g2
    int i6 = i >> 6, i63 = i & 63;
    bool inb = ((lane >> 3) == i6);             // lane's 8 elems share j>>6
    float sel1 = inb ? (g[1] + 1.0f) : g[0];
    float sel0 = inb ? g[1] : g[2];
    int lane8 = (lane & 7) * 8;
    // row softmax without max-subtract (|av| <= ~30 -> exp safe in fp32)
    float e[8], ls = 0.f;
    #pragma unroll
    for (int t = 0; t < 8; ++t) {
        bool ing = (lane8 + t) == i63;
        float av = v[t] * (ing ? sel1 : sel0);
        e[t] = __expf(av);
        ls += e[t];
    }
    #pragma unroll
    for (int off = 1; off < 64; off <<= 1) ls += __shfl_xor(ls, off);
    float inv = 1.0f / ls;
    union { ushort u[8]; int4 vv; } pk;
    #pragma unroll
    for (int t = 0; t < 8; ++t) pk.u[t] = f2bf(e[t] * inv);
    *(int4*)&adjb[(size_t)row * kL + j0] = pk.vv;
}

// ---------------------------------------------------------------------------
// K6 (merged): blocks 0..511: out = adjb @ xpbT (MFMA);
// blocks 512..549: loss stage 1 (imps col-sums + entropy partials).
// ---------------------------------------------------------------------------
__global__ __launch_bounds__(256) void k_out_loss1(const ushort* __restrict__ adjb,
        const ushort* __restrict__ xpbT, float* __restrict__ out,
        const float* __restrict__ spbuf, const float* __restrict__ entbuf,
        float* __restrict__ imps_buf, float* __restrict__ entpart) {
    int tid = threadIdx.x;
    int blk = blockIdx.x;
    if (blk < 512) {
        // ---------------- out branch ----------------
        __shared__ ushort as_[64][72];
        __shared__ ushort bs_[64][72];
        int bh = blk >> 3, it = blk & 7;
        int b = bh >> 3, h = bh & 7;
        int lane = tid & 63, wave = tid >> 6;
        int wm = wave >> 1, wn = wave & 1;
        int r = tid >> 2, s = tid & 3;
        const ushort* aG = adjb + ((size_t)(bh * kL + it * 64 + r)) * kL + s * 16;
        const ushort* bG = xpbT + ((size_t)(h * kDH + r)) * (size_t)(kB * kL) + b * kL + s * 16;
        f32x4 acc[2][2] = {};
        int am = wm * 32 + (lane & 15);
        int bn = wn * 32 + (lane & 15);
        int coff = (lane >> 4) * 8;
        for (int kt = 0; kt < 8; ++kt) {
            int4 a0 = *(const int4*)(aG + kt * 64);
            int4 a1 = *(const int4*)(aG + kt * 64 + 8);
            int4 b0 = *(const int4*)(bG + kt * 64);
            int4 b1 = *(const int4*)(bG + kt * 64 + 8);
            __syncthreads();
            *(int4*)&as_[r][s * 16] = a0;
            *(int4*)&as_[r][s * 16 + 8] = a1;
            *(int4*)&bs_[r][s * 16] = b0;
            *(int4*)&bs_[r][s * 16 + 8] = b1;
            __syncthreads();
            #pragma unroll
            for (int kk = 0; kk < 2; ++kk) {
                bf16x8 af[2], bf[2];
                #pragma unroll
                for (int fm = 0; fm < 2; ++fm)
                    af[fm] = *(const bf16x8*)&as_[am + fm * 16][kk * 32 + coff];
                #pragma unroll
                for (int fn = 0; fn < 2; ++fn)
                    bf[fn] = *(const bf16x8*)&bs_[bn + fn * 16][kk * 32 + coff];
                #pragma unroll
                for (int fm = 0; fm < 2; ++fm)
                    #pragma unroll
                    for (int fn = 0; fn < 2; ++fn)
                        acc[fm][fn] = __builtin_amdgcn_mfma_f32_16x16x32_bf16(
                            af[fm], bf[fn], acc[fm][fn], 0, 0, 0);
            }
        }
        int mrow = it * 64 + wm * 32 + (lane >> 4) * 4;
        int ncol = h * kDH + wn * 32 + (lane & 15);
        #pragma unroll
        for (int fm = 0; fm < 2; ++fm)
            #pragma unroll
            for (int fn = 0; fn < 2; ++fn)
                #pragma unroll
                for (int rr = 0; rr < 4; ++rr)
                    out[((size_t)b * kL + mrow + fm * 16 + rr) * kD + ncol + fn * 16] =
                        acc[fm][fn][rr];
    } else {
        // ---------------- loss stage 1 branch ----------------
        int lb = blk - 512;
        if (lb < 6) {
            int idx = lb * 256 + tid;      // < 1536
            float s = 0.f;
            for (int bh = 0; bh < kBH; ++bh)
                s += spbuf[bh * (kL * 3) + idx];
            imps_buf[idx] = s;
        } else {
            int eb = lb - 6;               // 0..31
            const float* src = entbuf + eb * 1024 + tid * 4;
            float4 v4 = *(const float4*)src;
            float s = v4.x + v4.y + v4.z + v4.w;
            __shared__ float red[256];
            red[tid] = s;
            __syncthreads();
            for (int st = 128; st > 0; st >>= 1) {
                if (tid < st) red[tid] += red[tid + st];
                __syncthreads();
            }
            if (tid == 0) entpart[eb] = red[0];
        }
    }
}

// ---------------------------------------------------------------------------
// K7b: loss stage 2 (single block): mean/var of imps (ddof=1) + entropy total
// ---------------------------------------------------------------------------
__global__ __launch_bounds__(256) void k_loss2(const float* __restrict__ imps_buf,
        const float* __restrict__ entpart, float* __restrict__ out_loss) {
    __shared__ float red[256];
    int tid = threadIdx.x;
    float im[6];
    #pragma unroll
    for (int t = 0; t < 6; ++t) im[t] = imps_buf[t * 256 + tid];
    float ms = im[0] + im[1] + im[2] + im[3] + im[4] + im[5];
    red[tid] = ms;
    __syncthreads();
    for (int st = 128; st > 0; st >>= 1) {
        if (tid < st) red[tid] += red[tid + st];
        __syncthreads();
    }
    float mean = red[0] / (float)(kL * 3);
    __syncthreads();
    float vs = 0.f;
    #pragma unroll
    for (int t = 0; t < 6; ++t) { float d = im[t] - mean; vs = fmaf(d, d, vs); }
    red[tid] = vs;
    __syncthreads();
    for (int st = 128; st > 0; st >>= 1) {
        if (tid < st) red[tid] += red[tid + st];
        __syncthreads();
    }
    float var = red[0] / (float)(kL * 3 - 1);
    __syncthreads();
    red[tid] = (tid < 32) ? entpart[tid] : 0.f;
    __syncthreads();
    for (int st = 128; st > 0; st >>= 1) {
        if (tid < st) red[tid] += red[tid + st];
        __syncthreads();
    }
    if (tid == 0) {
        float loss_imp = var / (mean * mean + 1e-10f);
        float loss_dyn = -red[0] / (float)(kBH * 3);
        out_loss[0] = loss_imp + 0.1f * loss_dyn;
    }
}

// ---------------------------------------------------------------------------
extern "C" void kernel_launch(void* const* d_in, const int* in_sizes, int n_in,
                              void* d_out, int out_size, void* d_ws, size_t ws_size,
                              hipStream_t stream) {
    const float* x     = (const float*)d_in[0];
    const float* W1    = (const float*)d_in[2];
    const float* b1    = (const float*)d_in[3];
    const float* W2    = (const float*)d_in[4];
    const float* b2    = (const float*)d_in[5];
    const float* Wg    = (const float*)d_in[6];
    const float* Wp    = (const float*)d_in[7];
    const float* bp    = (const float*)d_in[8];
    float* out = (float*)d_out;
    float* ws  = (float*)d_ws;

    // workspace layout (float units). adjb overlays qh/ql/kh/kl (dead after
    // k_adj; stream order serializes k_adj -> k_select).
    float*  adj    = ws;                          // [0, 16777216)
    ushort* qh     = (ushort*)(ws + 16777216);
    ushort* ql     = (ushort*)(ws + 17825792);
    ushort* kh     = (ushort*)(ws + 18874368);
    ushort* kl     = (ushort*)(ws + 19922944);
    ushort* adjb   = (ushort*)(ws + 16777216);    // overlays qh..kl + extra
    ushort* xpbT   = (ushort*)(ws + 25165824);
    float*  spbuf  = ws + 26214400;               // 98,304
    float*  entbuf = ws + 26312704;               // 32,768
    float*  imps_b = ws + 26345472;               // 1,536
    float*  entprt = ws + 26347008;               // 32

    k_qk_xp<<<1024, 256, 0, stream>>>(x, W1, b1, W2, b2, Wp, bp,
                                      qh, ql, kh, kl, xpbT);
    k_adj<<<kBH * 64, 256, 0, stream>>>(qh, ql, kh, kl, adj);
    k_select<<<kROWS / 4, 256, 0, stream>>>(adj, Wg, adjb, spbuf, entbuf);
    k_out_loss1<<<550, 256, 0, stream>>>(adjb, xpbT, out, spbuf, entbuf,
                                         imps_b, entprt);
    k_loss2<<<1, 256, 0, stream>>>(imps_b, entprt, out + (size_t)kB * kL * kD);
}